// Round 7
// baseline (700.136 us; speedup 1.0000x reference)
//
#include <hip/hip_runtime.h>
#include <hip/hip_cooperative_groups.h>
#include <hip/hip_bf16.h>
#include <math.h>

namespace cg = cooperative_groups;

#define B_  64
#define D_  512
#define NQ  8
#define NL  4

typedef __bf16 bf16;
typedef float  f32x4  __attribute__((ext_vector_type(4)));
typedef bf16   bf16x8 __attribute__((ext_vector_type(8)));

__device__ __forceinline__ void async_load16(const bf16* g, bf16* l) {
    __builtin_amdgcn_global_load_lds(
        (const __attribute__((address_space(1))) void*)g,
        (__attribute__((address_space(3))) void*)l, 16, 0, 0);
}

__device__ __forceinline__ void conv8(const float* __restrict__ s, bf16* __restrict__ d) {
    const float4 v0 = *(const float4*)s;
    const float4 v1 = *(const float4*)(s + 4);
    bf16x8 p;
    p[0] = (bf16)v0.x; p[1] = (bf16)v0.y; p[2] = (bf16)v0.z; p[3] = (bf16)v0.w;
    p[4] = (bf16)v1.x; p[5] = (bf16)v1.y; p[6] = (bf16)v1.z; p[7] = (bf16)v1.w;
    *(bf16x8*)d = p;
}

// ---------------------------------------------------------------------------
// One 128x128 tile of the NT GEMM (proven R2 structure, 44.4 us/dispatch):
// BK=64, 2-phase double-buffer (prefetch buf^1, compute buf, 1 barrier/step),
// chunk-XOR swizzle (slot s of row r holds global chunk s^(r&7), 0 bank
// conflicts measured), XCD-clustered virtual-tile decode.
// Epilogue loops fully unrolled (rule #20: runtime-indexed ext_vector ->
// scratch; R4/R5's 655 MB WRITE_SIZE regression).
// ---------------------------------------------------------------------------
template <int GELU>
__device__ __forceinline__ void gemm128_tile(const bf16* __restrict__ A,
                                             const bf16* __restrict__ Bv,
                                             const float* __restrict__ bias,
                                             void* __restrict__ Cout,
                                             int v, int t,
                                             bf16* __restrict__ As,
                                             bf16* __restrict__ Bs) {
    const int xcd  = v & 7;
    const int idx  = v >> 3;                 // 0..127
    const int b    = (xcd << 3) | (idx >> 4);
    const int tile = idx & 15;
    const int m0   = (tile >> 2) * 128;
    const int n0   = (tile & 3) * 128;

    const int lane = t & 63;
    const int w    = t >> 6;
    const int wr   = (w >> 1) * 64;
    const int wc   = (w & 1) * 64;
    const int l15  = lane & 15;
    const int quad = lane >> 4;

    f32x4 acc[4][4];
    #pragma unroll
    for (int i = 0; i < 4; i++)
        #pragma unroll
        for (int j = 0; j < 4; j++) acc[i][j] = (f32x4)(0.0f);

    const bf16* Bb = Bv + (size_t)b * D_ * D_;

    const int rl = lane >> 3;
    const int ck = (lane & 7) ^ rl;

    // prologue: stage K-tile 0 into buffer 0
    #pragma unroll
    for (int j = 0; j < 4; j++) {
        const int rbase = w * 32 + j * 8;
        async_load16(A  + (size_t)(m0 + rbase + rl) * D_ + ck * 8, As + rbase * 64);
        async_load16(Bb + (size_t)(n0 + rbase + rl) * D_ + ck * 8, Bs + rbase * 64);
    }
    __syncthreads();

    #pragma unroll 1
    for (int s = 0; s < 8; s++) {
        const int p = s & 1;
        const bf16* Asp = As + p * (128 * 64);
        const bf16* Bsp = Bs + p * (128 * 64);
        if (s < 7) {   // prefetch next K-tile into the other buffer
            const int k0 = (s + 1) * 64;
            bf16* Asn = As + (p ^ 1) * (128 * 64);
            bf16* Bsn = Bs + (p ^ 1) * (128 * 64);
            #pragma unroll
            for (int j = 0; j < 4; j++) {
                const int rbase = w * 32 + j * 8;
                async_load16(A  + (size_t)(m0 + rbase + rl) * D_ + k0 + ck * 8, Asn + rbase * 64);
                async_load16(Bb + (size_t)(n0 + rbase + rl) * D_ + k0 + ck * 8, Bsn + rbase * 64);
            }
        }
        #pragma unroll
        for (int kk = 0; kk < 2; kk++) {
            bf16x8 af[4], bfr[4];
            #pragma unroll
            for (int mt = 0; mt < 4; mt++) {
                const int row = wr + mt * 16 + l15;
                const int sl  = (kk * 4 + quad) ^ (l15 & 7);
                af[mt] = *(const bf16x8*)&Asp[row * 64 + sl * 8];
            }
            #pragma unroll
            for (int nt = 0; nt < 4; nt++) {
                const int row = wc + nt * 16 + l15;
                const int sl  = (kk * 4 + quad) ^ (l15 & 7);
                bfr[nt] = *(const bf16x8*)&Bsp[row * 64 + sl * 8];
            }
            #pragma unroll
            for (int mt = 0; mt < 4; mt++)
                #pragma unroll
                for (int nt = 0; nt < 4; nt++)
                    acc[mt][nt] = __builtin_amdgcn_mfma_f32_16x16x32_bf16(af[mt], bfr[nt], acc[mt][nt], 0, 0, 0);
        }
        __syncthreads();
    }

    if (GELU == 0) {
        bf16* Cb = (bf16*)Cout + (size_t)b * D_ * D_;
        #pragma unroll
        for (int mt = 0; mt < 4; mt++) {
            int row = m0 + wr + mt * 16 + quad * 4;
            #pragma unroll
            for (int nt = 0; nt < 4; nt++) {
                int col = n0 + wc + nt * 16 + l15;
                #pragma unroll
                for (int r = 0; r < 4; r++)
                    Cb[(size_t)(row + r) * D_ + col] = (bf16)acc[mt][nt][r];
            }
        }
    } else {
        float* Cb = (float*)Cout + (size_t)b * D_ * D_;
        #pragma unroll
        for (int mt = 0; mt < 4; mt++) {
            int row = m0 + wr + mt * 16 + quad * 4;
            #pragma unroll
            for (int nt = 0; nt < 4; nt++) {
                int col = n0 + wc + nt * 16 + l15;
                float bv = bias[col];
                #pragma unroll
                for (int r = 0; r < 4; r++) {
                    float v2 = acc[mt][nt][r] + bv;
                    Cb[(size_t)(row + r) * D_ + col] = 0.5f * v2 * (1.0f + erff(v2 * 0.70710678118654752f));
                }
            }
        }
    }
}

// ---------------------------------------------------------------------------
// Quantum circuit body: one wave handles batch b (validated R2/R3).
// ---------------------------------------------------------------------------
__device__ void quantum_body(float* __restrict__ out,
                             const float* __restrict__ pre_w,
                             const float* __restrict__ pre_b,
                             const float* __restrict__ post_w,
                             const float* __restrict__ post_b,
                             const float* __restrict__ qw,
                             int b, int l) {
    float* row0 = out + (size_t)b * D_ * D_;

    float tg[8];
    #pragma unroll
    for (int j = 0; j < 8; j++) tg[j] = row0[l + 64 * j];

    float ang[NQ];
    #pragma unroll
    for (int q = 0; q < NQ; q++) {
        float s = 0.f;
        #pragma unroll
        for (int j = 0; j < 8; j++) s += tg[j] * pre_w[q * D_ + l + 64 * j];
        #pragma unroll
        for (int m = 32; m >= 1; m >>= 1) s += __shfl_xor(s, m, 64);
        ang[q] = tanhf(s + pre_b[q]) * 3.14159265358979323846f;
    }

    float cw[NQ], sw[NQ];
    #pragma unroll
    for (int w = 0; w < NQ; w++) { cw[w] = cosf(0.5f * ang[w]); sw[w] = sinf(0.5f * ang[w]); }
    float re[4], im[4];
    #pragma unroll
    for (int r = 0; r < 4; r++) {
        int idx = l * 4 + r;
        float a = 1.f;
        #pragma unroll
        for (int w = 0; w < NQ; w++) a *= ((idx >> (7 - w)) & 1) ? sw[w] : cw[w];
        re[r] = a; im[r] = 0.f;
    }

    for (int lay = 0; lay < NL; lay++) {
        #pragma unroll
        for (int w = 0; w < 6; w++) {
            float th = 0.5f * qw[lay * NQ + w];
            float c = cosf(th), s = sinf(th);
            int m = 1 << (5 - w);
            #pragma unroll
            for (int r = 0; r < 4; r++) {
                float pre_ = __shfl_xor(re[r], m, 64);
                float pim_ = __shfl_xor(im[r], m, 64);
                re[r] = c * re[r] + s * pim_;
                im[r] = c * im[r] - s * pre_;
            }
        }
        {   // qubit 6 (bit 1): partner r^2
            float th = 0.5f * qw[lay * NQ + 6];
            float c = cosf(th), s = sinf(th);
            float or0 = re[0], or1 = re[1], or2 = re[2], or3 = re[3];
            float oi0 = im[0], oi1 = im[1], oi2 = im[2], oi3 = im[3];
            re[0] = c * or0 + s * oi2;  im[0] = c * oi0 - s * or2;
            re[1] = c * or1 + s * oi3;  im[1] = c * oi1 - s * or3;
            re[2] = c * or2 + s * oi0;  im[2] = c * oi2 - s * or0;
            re[3] = c * or3 + s * oi1;  im[3] = c * oi3 - s * or1;
        }
        {   // qubit 7 (bit 0): partner r^1
            float th = 0.5f * qw[lay * NQ + 7];
            float c = cosf(th), s = sinf(th);
            float or0 = re[0], or1 = re[1], or2 = re[2], or3 = re[3];
            float oi0 = im[0], oi1 = im[1], oi2 = im[2], oi3 = im[3];
            re[0] = c * or0 + s * oi1;  im[0] = c * oi0 - s * or1;
            re[1] = c * or1 + s * oi0;  im[1] = c * oi1 - s * or0;
            re[2] = c * or2 + s * oi3;  im[2] = c * oi2 - s * or3;
            re[3] = c * or3 + s * oi2;  im[3] = c * oi3 - s * or2;
        }
        #pragma unroll
        for (int w = 0; w < 5; w++) {
            int cb = 7 - w, tb = 6 - w;
            int tm = 1 << (tb - 2);
            bool ctl = (l >> (cb - 2)) & 1;
            #pragma unroll
            for (int r = 0; r < 4; r++) {
                float pre_ = __shfl_xor(re[r], tm, 64);
                float pim_ = __shfl_xor(im[r], tm, 64);
                re[r] = ctl ? pre_ : re[r];
                im[r] = ctl ? pim_ : im[r];
            }
        }
        {   // (5,6)
            bool ctl = l & 1;
            float t0 = re[0], t1 = re[1], t2 = re[2], t3 = re[3];
            float u0 = im[0], u1 = im[1], u2 = im[2], u3 = im[3];
            re[0] = ctl ? t2 : t0;  re[1] = ctl ? t3 : t1;
            re[2] = ctl ? t0 : t2;  re[3] = ctl ? t1 : t3;
            im[0] = ctl ? u2 : u0;  im[1] = ctl ? u3 : u1;
            im[2] = ctl ? u0 : u2;  im[3] = ctl ? u1 : u3;
        }
        {   // (6,7)
            float t2 = re[2], t3 = re[3], u2 = im[2], u3 = im[3];
            re[2] = t3; re[3] = t2; im[2] = u3; im[3] = u2;
        }
        {   // (7,0)
            #pragma unroll
            for (int r = 0; r < 4; r++) {
                float pre_ = __shfl_xor(re[r], 32, 64);
                float pim_ = __shfl_xor(im[r], 32, 64);
                if (r & 1) { re[r] = pre_; im[r] = pim_; }
            }
        }
    }

    float pr[4];
    #pragma unroll
    for (int r = 0; r < 4; r++) pr[r] = re[r] * re[r] + im[r] * im[r];
    float z[NQ];
    #pragma unroll
    for (int q = 0; q < NQ; q++) {
        int bit = 7 - q;
        float s = 0.f;
        #pragma unroll
        for (int r = 0; r < 4; r++) {
            int idx = l * 4 + r;
            s += ((idx >> bit) & 1) ? -pr[r] : pr[r];
        }
        #pragma unroll
        for (int m = 32; m >= 1; m >>= 1) s += __shfl_xor(s, m, 64);
        z[q] = s;
    }

    #pragma unroll
    for (int j = 0; j < 8; j++) {
        int h = l + 64 * j;
        float v = post_b[h];
        #pragma unroll
        for (int q = 0; q < NQ; q++) v += z[q] * post_w[h * NQ + q];
        row0[h] = v;
    }
}

// ---------------------------------------------------------------------------
// Cooperative mega-kernel: convert -> gemm1 -> gemm2 -> quantum, one launch.
// 512 blocks x 256 thr, 64 KB LDS -> 2 blocks/CU, all 512 resident.
// grid.sync() + __threadfence() between phases (cross-XCD visibility).
// Each block runs 2 virtual 128^2 tiles per gemm phase: v = blk, blk+512
// (512 == 0 mod 8 -> same XCD slot in the decode, remap preserved).
// ---------------------------------------------------------------------------
__global__ __launch_bounds__(256, 2) void mega(const float* __restrict__ x,
                                               const float* __restrict__ W,
                                               const float* __restrict__ adj,
                                               const float* __restrict__ bias,
                                               const float* __restrict__ pre_w,
                                               const float* __restrict__ pre_b,
                                               const float* __restrict__ post_w,
                                               const float* __restrict__ post_b,
                                               const float* __restrict__ qw,
                                               bf16* __restrict__ xbf,
                                               bf16* __restrict__ Wbf,
                                               bf16* __restrict__ adjbf,
                                               bf16* __restrict__ Yt,
                                               float* __restrict__ out) {
    cg::grid_group grid = cg::this_grid();
    __shared__ bf16 As[2 * 128 * 64];
    __shared__ bf16 Bs[2 * 128 * 64];

    const int blk = blockIdx.x;
    const int t   = threadIdx.x;

    // ---- phase 0: fp32 -> bf16 converts (x, W, adj) ----
    {
        const int n8x = B_ * D_ * D_ / 8;
        const int n8m = D_ * D_ / 8;
        const int total = n8x + 2 * n8m;
        for (int i = blk * 256 + t; i < total; i += 512 * 256) {
            if (i < n8x)            conv8(x   + (size_t)i * 8,              xbf   + (size_t)i * 8);
            else if (i < n8x + n8m) conv8(W   + (size_t)(i - n8x) * 8,      Wbf   + (size_t)(i - n8x) * 8);
            else                    conv8(adj + (size_t)(i - n8x - n8m) * 8, adjbf + (size_t)(i - n8x - n8m) * 8);
        }
    }
    __threadfence();
    grid.sync();
    __threadfence();

    // ---- phase 1: Yt[b][g][j] = sum_h W[g][h] * x[b][j][h] ----
    gemm128_tile<0>(Wbf, xbf, nullptr, (void*)Yt, blk,       t, As, Bs);
    gemm128_tile<0>(Wbf, xbf, nullptr, (void*)Yt, blk + 512, t, As, Bs);
    __threadfence();
    grid.sync();
    __threadfence();

    // ---- phase 2: out[b][i][g] = gelu( sum_j adj[i][j]*Yt[b][g][j] + bias ) ----
    gemm128_tile<1>(adjbf, Yt, bias, (void*)out, blk,       t, As, Bs);
    gemm128_tile<1>(adjbf, Yt, bias, (void*)out, blk + 512, t, As, Bs);
    __threadfence();
    grid.sync();
    __threadfence();

    // ---- phase 3: quantum on target row (64 batches, wave 0 of blocks 0-63) ----
    if (blk < 64 && t < 64)
        quantum_body(out, pre_w, pre_b, post_w, post_b, qw, blk, t);
}

// ---------------------------------------------------------------------------
// Fallback standalone kernels (non-cooperative path)
// ---------------------------------------------------------------------------
__global__ __launch_bounds__(256) void convert_all_k(const float* __restrict__ x,
                                                     const float* __restrict__ w,
                                                     const float* __restrict__ adj,
                                                     bf16* __restrict__ xbf,
                                                     bf16* __restrict__ wbf,
                                                     bf16* __restrict__ adjbf,
                                                     int n8x, int n8m) {
    const int total = n8x + 2 * n8m;
    for (int i = blockIdx.x * 256 + threadIdx.x; i < total; i += gridDim.x * 256) {
        if (i < n8x)            conv8(x   + (size_t)i * 8,               xbf   + (size_t)i * 8);
        else if (i < n8x + n8m) conv8(w   + (size_t)(i - n8x) * 8,       wbf   + (size_t)(i - n8x) * 8);
        else                    conv8(adj + (size_t)(i - n8x - n8m) * 8,  adjbf + (size_t)(i - n8x - n8m) * 8);
    }
}

template <int GELU>
__global__ __launch_bounds__(256) void gemm128_k(const bf16* __restrict__ A,
                                                 const bf16* __restrict__ Bv,
                                                 const float* __restrict__ bias,
                                                 void* __restrict__ Cout) {
    __shared__ bf16 As[2 * 128 * 64];
    __shared__ bf16 Bs[2 * 128 * 64];
    const int v = blockIdx.y * 16 + blockIdx.x;
    gemm128_tile<GELU>(A, Bv, bias, Cout, v, threadIdx.x, As, Bs);
}

__global__ __launch_bounds__(64) void quantum_k(float* __restrict__ out,
                                                const float* __restrict__ pre_w,
                                                const float* __restrict__ pre_b,
                                                const float* __restrict__ post_w,
                                                const float* __restrict__ post_b,
                                                const float* __restrict__ qw) {
    quantum_body(out, pre_w, pre_b, post_w, post_b, qw, blockIdx.x, threadIdx.x);
}

// ---------------------------------------------------------------------------
// Legacy GEMM (fallback if ws too small for bf16 copies)
// ---------------------------------------------------------------------------
__global__ __launch_bounds__(256) void convert_kernel(const float* __restrict__ src,
                                                      bf16* __restrict__ dst, int n8) {
    int i = blockIdx.x * 256 + threadIdx.x;
    if (i < n8) conv8(src + (size_t)i * 8, dst + (size_t)i * 8);
}

#define PITCH 40
template <int GELU>
__global__ __launch_bounds__(256) void gemm_nt_legacy(const float* __restrict__ A,
                                                      const bf16* __restrict__ Bv,
                                                      const float* __restrict__ bias,
                                                      void* __restrict__ Cout) {
    __shared__ bf16 As[128 * PITCH];
    __shared__ bf16 Bs[128 * 32];
    const int b    = blockIdx.y;
    const int tile = blockIdx.x;
    const int m0   = (tile >> 2) * 128;
    const int n0   = (tile & 3) * 128;
    const int t    = threadIdx.x;
    const int lane = t & 63;
    const int w    = t >> 6;
    const int wr   = (w >> 1) * 64;
    const int wc   = (w & 1) * 64;
    const int l15  = lane & 15;
    const int quad = lane >> 4;

    f32x4 acc[4][4];
    #pragma unroll
    for (int i = 0; i < 4; i++)
        #pragma unroll
        for (int j = 0; j < 4; j++) acc[i][j] = (f32x4)(0.0f);

    const bf16* Bb = Bv + (size_t)b * D_ * D_;

    for (int k0 = 0; k0 < D_; k0 += 32) {
        for (int c = t; c < 512; c += 256) {
            int row = c >> 2, ch = c & 3;
            const float* s = A + (size_t)(m0 + row) * D_ + k0 + ch * 8;
            const float4 v0 = *(const float4*)s;
            const float4 v1 = *(const float4*)(s + 4);
            bf16x8 p;
            p[0] = (bf16)v0.x; p[1] = (bf16)v0.y; p[2] = (bf16)v0.z; p[3] = (bf16)v0.w;
            p[4] = (bf16)v1.x; p[5] = (bf16)v1.y; p[6] = (bf16)v1.z; p[7] = (bf16)v1.w;
            *(bf16x8*)&As[row * PITCH + ch * 8] = p;
        }
        {
            int rl = lane >> 2;
            int kchunk = (lane & 3) ^ ((lane >> 3) & 3);
            #pragma unroll
            for (int j = 0; j < 2; j++) {
                int rbase = w * 32 + j * 16;
                async_load16(Bb + (size_t)(n0 + rbase + rl) * D_ + k0 + kchunk * 8, &Bs[rbase * 32]);
            }
        }
        __syncthreads();
        bf16x8 af[4], bfr[4];
        #pragma unroll
        for (int mt = 0; mt < 4; mt++)
            af[mt] = *(const bf16x8*)&As[(wr + mt * 16 + l15) * PITCH + quad * 8];
        #pragma unroll
        for (int nt = 0; nt < 4; nt++) {
            int row = wc + nt * 16 + l15;
            int kx  = quad ^ ((l15 >> 1) & 3);
            bfr[nt] = *(const bf16x8*)&Bs[row * 32 + kx * 8];
        }
        #pragma unroll
        for (int mt = 0; mt < 4; mt++)
            #pragma unroll
            for (int nt = 0; nt < 4; nt++)
                acc[mt][nt] = __builtin_amdgcn_mfma_f32_16x16x32_bf16(af[mt], bfr[nt], acc[mt][nt], 0, 0, 0);
        __syncthreads();
    }

    if (GELU == 0) {
        bf16* Cb = (bf16*)Cout + (size_t)b * D_ * D_;
        #pragma unroll
        for (int mt = 0; mt < 4; mt++) {
            int row = m0 + wr + mt * 16 + quad * 4;
            #pragma unroll
            for (int nt = 0; nt < 4; nt++) {
                int col = n0 + wc + nt * 16 + l15;
                #pragma unroll
                for (int r = 0; r < 4; r++)
                    Cb[(size_t)(row + r) * D_ + col] = (bf16)acc[mt][nt][r];
            }
        }
    } else {
        float* Cb = (float*)Cout + (size_t)b * D_ * D_;
        #pragma unroll
        for (int mt = 0; mt < 4; mt++) {
            int row = m0 + wr + mt * 16 + quad * 4;
            #pragma unroll
            for (int nt = 0; nt < 4; nt++) {
                int col = n0 + wc + nt * 16 + l15;
                float bv = bias[col];
                #pragma unroll
                for (int r = 0; r < 4; r++) {
                    float v = acc[mt][nt][r] + bv;
                    Cb[(size_t)(row + r) * D_ + col] = 0.5f * v * (1.0f + erff(v * 0.70710678118654752f));
                }
            }
        }
    }
}

// ---------------------------------------------------------------------------
extern "C" void kernel_launch(void* const* d_in, const int* in_sizes, int n_in,
                              void* d_out, int out_size, void* d_ws, size_t ws_size,
                              hipStream_t stream) {
    const float* x        = (const float*)d_in[0];
    const float* norm_adj = (const float*)d_in[1];
    const float* W_gcn_w  = (const float*)d_in[2];
    const float* W_gcn_b  = (const float*)d_in[3];
    const float* pre_w    = (const float*)d_in[4];
    const float* pre_b    = (const float*)d_in[5];
    const float* post_w   = (const float*)d_in[6];
    const float* post_b   = (const float*)d_in[7];
    const float* q_w      = (const float*)d_in[8];
    float* out = (float*)d_out;

    bf16* xbf = (bf16*)d_out;            // first 32 MiB of d_out: dead until gemm2 writes
    bf16* Yt  = (bf16*)d_ws;             // 32 MiB

    const int n8_x = B_ * D_ * D_ / 8;
    const int n8_m = D_ * D_ / 8;

    const size_t MB32 = (size_t)32 * 1024 * 1024;
    if (ws_size >= MB32 + 2 * 1024 * 1024) {
        bf16* Wbf   = (bf16*)((char*)d_ws + MB32);
        bf16* adjbf = Wbf + D_ * D_;

        void* args[] = {
            (void*)&x, (void*)&W_gcn_w, (void*)&norm_adj, (void*)&W_gcn_b,
            (void*)&pre_w, (void*)&pre_b, (void*)&post_w, (void*)&post_b,
            (void*)&q_w, (void*)&xbf, (void*)&Wbf, (void*)&adjbf,
            (void*)&Yt, (void*)&out
        };
        hipError_t e = hipLaunchCooperativeKernel((const void*)mega,
                                                  dim3(512), dim3(256),
                                                  args, 0, stream);
        if (e != hipSuccess) {
            // fallback: proven R2-style multi-kernel pipeline
            convert_all_k<<<2048, 256, 0, stream>>>(x, W_gcn_w, norm_adj,
                                                    xbf, Wbf, adjbf, n8_x, n8_m);
            dim3 grid(16, B_);
            gemm128_k<0><<<grid, 256, 0, stream>>>(Wbf, xbf, nullptr, (void*)Yt);
            gemm128_k<1><<<grid, 256, 0, stream>>>(adjbf, Yt, W_gcn_b, (void*)out);
            quantum_k<<<B_, 64, 0, stream>>>(out, pre_w, pre_b, post_w, post_b, q_w);
        }
    } else {
        dim3 grid(16, B_);
        convert_kernel<<<(n8_x + 255) / 256, 256, 0, stream>>>(x, xbf, n8_x);
        gemm_nt_legacy<0><<<grid, 256, 0, stream>>>(W_gcn_w, xbf, nullptr, (void*)Yt);
        gemm_nt_legacy<1><<<grid, 256, 0, stream>>>(norm_adj, Yt, W_gcn_b, (void*)out);
        quantum_k<<<B_, 64, 0, stream>>>(out, pre_w, pre_b, post_w, post_b, q_w);
    }
}

// Round 8
// 193.663 us; speedup vs baseline: 3.6152x; 3.6152x over previous
//
#include <hip/hip_runtime.h>
#include <hip/hip_bf16.h>
#include <math.h>

#define B_  64
#define D_  512
#define NQ  8
#define NL  4

typedef __bf16 bf16;
typedef float  f32x4  __attribute__((ext_vector_type(4)));
typedef bf16   bf16x8 __attribute__((ext_vector_type(8)));

__device__ __forceinline__ void async_load16(const bf16* g, bf16* l) {
    __builtin_amdgcn_global_load_lds(
        (const __attribute__((address_space(1))) void*)g,
        (__attribute__((address_space(3))) void*)l, 16, 0, 0);
}

__device__ __forceinline__ void conv8(const float* __restrict__ s, bf16* __restrict__ d) {
    const float4 v0 = *(const float4*)s;
    const float4 v1 = *(const float4*)(s + 4);
    bf16x8 p;
    p[0] = (bf16)v0.x; p[1] = (bf16)v0.y; p[2] = (bf16)v0.z; p[3] = (bf16)v0.w;
    p[4] = (bf16)v1.x; p[5] = (bf16)v1.y; p[6] = (bf16)v1.z; p[7] = (bf16)v1.w;
    *(bf16x8*)d = p;
}

// ---------------------------------------------------------------------------
// fp32 -> bf16 converts: x, W, adj in one grid-stride launch.
// ---------------------------------------------------------------------------
__global__ __launch_bounds__(256) void convert_all_k(const float* __restrict__ x,
                                                     const float* __restrict__ w,
                                                     const float* __restrict__ adj,
                                                     bf16* __restrict__ xbf,
                                                     bf16* __restrict__ wbf,
                                                     bf16* __restrict__ adjbf,
                                                     int n8x, int n8m) {
    const int total = n8x + 2 * n8m;
    for (int i = blockIdx.x * 256 + threadIdx.x; i < total; i += gridDim.x * 256) {
        if (i < n8x)            conv8(x   + (size_t)i * 8,               xbf   + (size_t)i * 8);
        else if (i < n8x + n8m) conv8(w   + (size_t)(i - n8x) * 8,       wbf   + (size_t)(i - n8x) * 8);
        else                    conv8(adj + (size_t)(i - n8x - n8m) * 8,  adjbf + (size_t)(i - n8x - n8m) * 8);
    }
}

// ---------------------------------------------------------------------------
// One 128x128 tile of the NT GEMM (proven R2 structure, 44.4 us/dispatch):
// BK=64, 2-phase double-buffer (prefetch buf^1, compute buf, 1 barrier/step),
// chunk-XOR swizzle (slot s of row r holds chunk s^(r&7); 0 conflicts
// measured), XCD-clustered virtual-tile decode (FETCH 35->20.7 MB).
// Epilogue fully unrolled (rule #20: runtime-indexed ext_vector -> scratch,
// the R4/R5 655 MB WRITE_SIZE regression).
// SKIP0 (gemm2 only): suppress row-0 stores — row 0 is wholly replaced by
// the quantum projection, computed by the fused quantum blocks.
// ---------------------------------------------------------------------------
template <int GELU, int SKIP0>
__device__ __forceinline__ void gemm128_tile(const bf16* __restrict__ A,
                                             const bf16* __restrict__ Bv,
                                             const float* __restrict__ bias,
                                             void* __restrict__ Cout,
                                             int v, int t,
                                             bf16* __restrict__ As,
                                             bf16* __restrict__ Bs) {
    const int xcd  = v & 7;
    const int idx  = v >> 3;                 // 0..127
    const int b    = (xcd << 3) | (idx >> 4);
    const int tile = idx & 15;
    const int m0   = (tile >> 2) * 128;
    const int n0   = (tile & 3) * 128;

    const int lane = t & 63;
    const int w    = t >> 6;
    const int wr   = (w >> 1) * 64;
    const int wc   = (w & 1) * 64;
    const int l15  = lane & 15;
    const int quad = lane >> 4;

    f32x4 acc[4][4];
    #pragma unroll
    for (int i = 0; i < 4; i++)
        #pragma unroll
        for (int j = 0; j < 4; j++) acc[i][j] = (f32x4)(0.0f);

    const bf16* Bb = Bv + (size_t)b * D_ * D_;

    const int rl = lane >> 3;
    const int ck = (lane & 7) ^ rl;

    // prologue: stage K-tile 0 into buffer 0
    #pragma unroll
    for (int j = 0; j < 4; j++) {
        const int rbase = w * 32 + j * 8;
        async_load16(A  + (size_t)(m0 + rbase + rl) * D_ + ck * 8, As + rbase * 64);
        async_load16(Bb + (size_t)(n0 + rbase + rl) * D_ + ck * 8, Bs + rbase * 64);
    }
    __syncthreads();

    #pragma unroll 1
    for (int s = 0; s < 8; s++) {
        const int p = s & 1;
        const bf16* Asp = As + p * (128 * 64);
        const bf16* Bsp = Bs + p * (128 * 64);
        if (s < 7) {   // prefetch next K-tile into the other buffer
            const int k0 = (s + 1) * 64;
            bf16* Asn = As + (p ^ 1) * (128 * 64);
            bf16* Bsn = Bs + (p ^ 1) * (128 * 64);
            #pragma unroll
            for (int j = 0; j < 4; j++) {
                const int rbase = w * 32 + j * 8;
                async_load16(A  + (size_t)(m0 + rbase + rl) * D_ + k0 + ck * 8, Asn + rbase * 64);
                async_load16(Bb + (size_t)(n0 + rbase + rl) * D_ + k0 + ck * 8, Bsn + rbase * 64);
            }
        }
        #pragma unroll
        for (int kk = 0; kk < 2; kk++) {
            bf16x8 af[4], bfr[4];
            #pragma unroll
            for (int mt = 0; mt < 4; mt++) {
                const int row = wr + mt * 16 + l15;
                const int sl  = (kk * 4 + quad) ^ (l15 & 7);
                af[mt] = *(const bf16x8*)&Asp[row * 64 + sl * 8];
            }
            #pragma unroll
            for (int nt = 0; nt < 4; nt++) {
                const int row = wc + nt * 16 + l15;
                const int sl  = (kk * 4 + quad) ^ (l15 & 7);
                bfr[nt] = *(const bf16x8*)&Bsp[row * 64 + sl * 8];
            }
            #pragma unroll
            for (int mt = 0; mt < 4; mt++)
                #pragma unroll
                for (int nt = 0; nt < 4; nt++)
                    acc[mt][nt] = __builtin_amdgcn_mfma_f32_16x16x32_bf16(af[mt], bfr[nt], acc[mt][nt], 0, 0, 0);
        }
        __syncthreads();
    }

    if (GELU == 0) {
        bf16* Cb = (bf16*)Cout + (size_t)b * D_ * D_;
        #pragma unroll
        for (int mt = 0; mt < 4; mt++) {
            int row = m0 + wr + mt * 16 + quad * 4;
            #pragma unroll
            for (int nt = 0; nt < 4; nt++) {
                int col = n0 + wc + nt * 16 + l15;
                #pragma unroll
                for (int r = 0; r < 4; r++)
                    Cb[(size_t)(row + r) * D_ + col] = (bf16)acc[mt][nt][r];
            }
        }
    } else {
        float* Cb = (float*)Cout + (size_t)b * D_ * D_;
        #pragma unroll
        for (int mt = 0; mt < 4; mt++) {
            int row = m0 + wr + mt * 16 + quad * 4;
            #pragma unroll
            for (int nt = 0; nt < 4; nt++) {
                int col = n0 + wc + nt * 16 + l15;
                float bv = bias[col];
                #pragma unroll
                for (int r = 0; r < 4; r++) {
                    if (SKIP0 && (row + r) == 0) continue;   // row 0 owned by quantum
                    float v2 = acc[mt][nt][r] + bv;
                    Cb[(size_t)(row + r) * D_ + col] = 0.5f * v2 * (1.0f + erff(v2 * 0.70710678118654752f));
                }
            }
        }
    }
}

// ---------------------------------------------------------------------------
// Quantum circuit core: one wave, lane l; tgt indexed [l + 64*j] (LDS or
// global), writes the post-projection into row0[0..511].
// ---------------------------------------------------------------------------
__device__ void quantum_core(const float* __restrict__ tgt,
                             float* __restrict__ row0,
                             const float* __restrict__ pre_w,
                             const float* __restrict__ pre_b,
                             const float* __restrict__ post_w,
                             const float* __restrict__ post_b,
                             const float* __restrict__ qw,
                             int l) {
    float tg[8];
    #pragma unroll
    for (int j = 0; j < 8; j++) tg[j] = tgt[l + 64 * j];

    float ang[NQ];
    #pragma unroll
    for (int q = 0; q < NQ; q++) {
        float s = 0.f;
        #pragma unroll
        for (int j = 0; j < 8; j++) s += tg[j] * pre_w[q * D_ + l + 64 * j];
        #pragma unroll
        for (int m = 32; m >= 1; m >>= 1) s += __shfl_xor(s, m, 64);
        ang[q] = tanhf(s + pre_b[q]) * 3.14159265358979323846f;
    }

    float cw[NQ], sw[NQ];
    #pragma unroll
    for (int w = 0; w < NQ; w++) { cw[w] = cosf(0.5f * ang[w]); sw[w] = sinf(0.5f * ang[w]); }
    float re[4], im[4];
    #pragma unroll
    for (int r = 0; r < 4; r++) {
        int idx = l * 4 + r;
        float a = 1.f;
        #pragma unroll
        for (int w = 0; w < NQ; w++) a *= ((idx >> (7 - w)) & 1) ? sw[w] : cw[w];
        re[r] = a; im[r] = 0.f;
    }

    for (int lay = 0; lay < NL; lay++) {
        #pragma unroll
        for (int w = 0; w < 6; w++) {
            float th = 0.5f * qw[lay * NQ + w];
            float c = cosf(th), s = sinf(th);
            int m = 1 << (5 - w);
            #pragma unroll
            for (int r = 0; r < 4; r++) {
                float pre_ = __shfl_xor(re[r], m, 64);
                float pim_ = __shfl_xor(im[r], m, 64);
                re[r] = c * re[r] + s * pim_;
                im[r] = c * im[r] - s * pre_;
            }
        }
        {   // qubit 6 (bit 1): partner r^2
            float th = 0.5f * qw[lay * NQ + 6];
            float c = cosf(th), s = sinf(th);
            float or0 = re[0], or1 = re[1], or2 = re[2], or3 = re[3];
            float oi0 = im[0], oi1 = im[1], oi2 = im[2], oi3 = im[3];
            re[0] = c * or0 + s * oi2;  im[0] = c * oi0 - s * or2;
            re[1] = c * or1 + s * oi3;  im[1] = c * oi1 - s * or3;
            re[2] = c * or2 + s * oi0;  im[2] = c * oi2 - s * or0;
            re[3] = c * or3 + s * oi1;  im[3] = c * oi3 - s * or1;
        }
        {   // qubit 7 (bit 0): partner r^1
            float th = 0.5f * qw[lay * NQ + 7];
            float c = cosf(th), s = sinf(th);
            float or0 = re[0], or1 = re[1], or2 = re[2], or3 = re[3];
            float oi0 = im[0], oi1 = im[1], oi2 = im[2], oi3 = im[3];
            re[0] = c * or0 + s * oi1;  im[0] = c * oi0 - s * or1;
            re[1] = c * or1 + s * oi0;  im[1] = c * oi1 - s * or0;
            re[2] = c * or2 + s * oi3;  im[2] = c * oi2 - s * or3;
            re[3] = c * or3 + s * oi2;  im[3] = c * oi3 - s * or2;
        }
        #pragma unroll
        for (int w = 0; w < 5; w++) {
            int cb = 7 - w, tb = 6 - w;
            int tm = 1 << (tb - 2);
            bool ctl = (l >> (cb - 2)) & 1;
            #pragma unroll
            for (int r = 0; r < 4; r++) {
                float pre_ = __shfl_xor(re[r], tm, 64);
                float pim_ = __shfl_xor(im[r], tm, 64);
                re[r] = ctl ? pre_ : re[r];
                im[r] = ctl ? pim_ : im[r];
            }
        }
        {   // (5,6)
            bool ctl = l & 1;
            float t0 = re[0], t1 = re[1], t2 = re[2], t3 = re[3];
            float u0 = im[0], u1 = im[1], u2 = im[2], u3 = im[3];
            re[0] = ctl ? t2 : t0;  re[1] = ctl ? t3 : t1;
            re[2] = ctl ? t0 : t2;  re[3] = ctl ? t1 : t3;
            im[0] = ctl ? u2 : u0;  im[1] = ctl ? u3 : u1;
            im[2] = ctl ? u0 : u2;  im[3] = ctl ? u1 : u3;
        }
        {   // (6,7)
            float t2 = re[2], t3 = re[3], u2 = im[2], u3 = im[3];
            re[2] = t3; re[3] = t2; im[2] = u3; im[3] = u2;
        }
        {   // (7,0)
            #pragma unroll
            for (int r = 0; r < 4; r++) {
                float pre_ = __shfl_xor(re[r], 32, 64);
                float pim_ = __shfl_xor(im[r], 32, 64);
                if (r & 1) { re[r] = pre_; im[r] = pim_; }
            }
        }
    }

    float pr[4];
    #pragma unroll
    for (int r = 0; r < 4; r++) pr[r] = re[r] * re[r] + im[r] * im[r];
    float z[NQ];
    #pragma unroll
    for (int q = 0; q < NQ; q++) {
        int bit = 7 - q;
        float s = 0.f;
        #pragma unroll
        for (int r = 0; r < 4; r++) {
            int idx = l * 4 + r;
            s += ((idx >> bit) & 1) ? -pr[r] : pr[r];
        }
        #pragma unroll
        for (int m = 32; m >= 1; m >>= 1) s += __shfl_xor(s, m, 64);
        z[q] = s;
    }

    #pragma unroll
    for (int j = 0; j < 8; j++) {
        int h = l + 64 * j;
        float v = post_b[h];
        #pragma unroll
        for (int q = 0; q < NQ; q++) v += z[q] * post_w[h * NQ + q];
        row0[h] = v;
    }
}

// ---------------------------------------------------------------------------
// gemm1: standalone proven 128^2 kernel.
// ---------------------------------------------------------------------------
__global__ __launch_bounds__(256) void gemm1_k(const bf16* __restrict__ A,
                                               const bf16* __restrict__ Bv,
                                               void* __restrict__ Cout) {
    __shared__ bf16 As[2 * 128 * 64];
    __shared__ bf16 Bs[2 * 128 * 64];
    const int v = blockIdx.y * 16 + blockIdx.x;
    gemm128_tile<0, 0>(A, Bv, nullptr, Cout, v, threadIdx.x, As, Bs);
}

// ---------------------------------------------------------------------------
// fused2: gemm2(+gelu, skip row 0) for blocks 64..1087, quantum for blocks
// 0..63 (placed FIRST so the long serial circuit overlaps the gemm bulk).
// Quantum block b: tgt[g] = gelu(adj_row0 . Yt[b][g][:] + bias[g]) computed
// from Yt directly (removes the quantum->gemm2 dependency; row 0 of out is
// disjointly owned by quantum, so no ordering needed between block groups).
// ---------------------------------------------------------------------------
__global__ __launch_bounds__(256) void fused2_k(const bf16* __restrict__ adjb,
                                                const bf16* __restrict__ Yt,
                                                const float* __restrict__ adj_f32,
                                                const float* __restrict__ bias,
                                                const float* __restrict__ pre_w,
                                                const float* __restrict__ pre_b,
                                                const float* __restrict__ post_w,
                                                const float* __restrict__ post_b,
                                                const float* __restrict__ qw,
                                                float* __restrict__ out) {
    __shared__ bf16 As[2 * 128 * 64];
    __shared__ bf16 Bs[2 * 128 * 64];
    const int t = threadIdx.x;
    const int v = blockIdx.x;

    if (v >= 64) {
        gemm128_tile<1, 1>(adjb, Yt, bias, (void*)out, v - 64, t, As, Bs);
        return;
    }

    // ---- quantum block for batch b = v ----
    const int b = v;
    float* tgt_s  = (float*)As;          // 2 KB alias into gemm LDS
    float* adj0_s = (float*)Bs;          // 2 KB

    for (int i = t; i < D_; i += 256) adj0_s[i] = adj_f32[i];   // adj row 0
    __syncthreads();

    const bf16* Ytb = Yt + (size_t)b * D_ * D_;
    for (int g = t; g < D_; g += 256) {
        const bf16* yrow = Ytb + (size_t)g * D_;
        float s = bias[g];
        #pragma unroll 4
        for (int j = 0; j < D_; j += 8) {
            bf16x8 yv = *(const bf16x8*)(yrow + j);
            #pragma unroll
            for (int u = 0; u < 8; u++) s += adj0_s[j + u] * (float)yv[u];
        }
        tgt_s[g] = 0.5f * s * (1.0f + erff(s * 0.70710678118654752f));
    }
    __syncthreads();

    if (t < 64)
        quantum_core(tgt_s, out + (size_t)b * D_ * D_,
                     pre_w, pre_b, post_w, post_b, qw, t);
}

// ---------------------------------------------------------------------------
// Legacy fallback kernels (ws too small for bf16 copies)
// ---------------------------------------------------------------------------
__global__ __launch_bounds__(256) void convert_kernel(const float* __restrict__ src,
                                                      bf16* __restrict__ dst, int n8) {
    int i = blockIdx.x * 256 + threadIdx.x;
    if (i < n8) conv8(src + (size_t)i * 8, dst + (size_t)i * 8);
}

__global__ __launch_bounds__(64) void quantum_k(float* __restrict__ out,
                                                const float* __restrict__ pre_w,
                                                const float* __restrict__ pre_b,
                                                const float* __restrict__ post_w,
                                                const float* __restrict__ post_b,
                                                const float* __restrict__ qw) {
    float* row0 = out + (size_t)blockIdx.x * D_ * D_;
    quantum_core(row0, row0, pre_w, pre_b, post_w, post_b, qw, threadIdx.x);
}

#define PITCH 40
template <int GELU>
__global__ __launch_bounds__(256) void gemm_nt_legacy(const float* __restrict__ A,
                                                      const bf16* __restrict__ Bv,
                                                      const float* __restrict__ bias,
                                                      void* __restrict__ Cout) {
    __shared__ bf16 As[128 * PITCH];
    __shared__ bf16 Bs[128 * 32];
    const int b    = blockIdx.y;
    const int tile = blockIdx.x;
    const int m0   = (tile >> 2) * 128;
    const int n0   = (tile & 3) * 128;
    const int t    = threadIdx.x;
    const int lane = t & 63;
    const int w    = t >> 6;
    const int wr   = (w >> 1) * 64;
    const int wc   = (w & 1) * 64;
    const int l15  = lane & 15;
    const int quad = lane >> 4;

    f32x4 acc[4][4];
    #pragma unroll
    for (int i = 0; i < 4; i++)
        #pragma unroll
        for (int j = 0; j < 4; j++) acc[i][j] = (f32x4)(0.0f);

    const bf16* Bb = Bv + (size_t)b * D_ * D_;

    for (int k0 = 0; k0 < D_; k0 += 32) {
        for (int c = t; c < 512; c += 256) {
            int row = c >> 2, ch = c & 3;
            const float* s = A + (size_t)(m0 + row) * D_ + k0 + ch * 8;
            const float4 v0 = *(const float4*)s;
            const float4 v1 = *(const float4*)(s + 4);
            bf16x8 p;
            p[0] = (bf16)v0.x; p[1] = (bf16)v0.y; p[2] = (bf16)v0.z; p[3] = (bf16)v0.w;
            p[4] = (bf16)v1.x; p[5] = (bf16)v1.y; p[6] = (bf16)v1.z; p[7] = (bf16)v1.w;
            *(bf16x8*)&As[row * PITCH + ch * 8] = p;
        }
        {
            int rl = lane >> 2;
            int kchunk = (lane & 3) ^ ((lane >> 3) & 3);
            #pragma unroll
            for (int j = 0; j < 2; j++) {
                int rbase = w * 32 + j * 16;
                async_load16(Bb + (size_t)(n0 + rbase + rl) * D_ + k0 + kchunk * 8, &Bs[rbase * 32]);
            }
        }
        __syncthreads();
        bf16x8 af[4], bfr[4];
        #pragma unroll
        for (int mt = 0; mt < 4; mt++)
            af[mt] = *(const bf16x8*)&As[(wr + mt * 16 + l15) * PITCH + quad * 8];
        #pragma unroll
        for (int nt = 0; nt < 4; nt++) {
            int row = wc + nt * 16 + l15;
            int kx  = quad ^ ((l15 >> 1) & 3);
            bfr[nt] = *(const bf16x8*)&Bs[row * 32 + kx * 8];
        }
        #pragma unroll
        for (int mt = 0; mt < 4; mt++)
            #pragma unroll
            for (int nt = 0; nt < 4; nt++)
                acc[mt][nt] = __builtin_amdgcn_mfma_f32_16x16x32_bf16(af[mt], bfr[nt], acc[mt][nt], 0, 0, 0);
        __syncthreads();
    }

    if (GELU == 0) {
        bf16* Cb = (bf16*)Cout + (size_t)b * D_ * D_;
        #pragma unroll
        for (int mt = 0; mt < 4; mt++) {
            int row = m0 + wr + mt * 16 + quad * 4;
            #pragma unroll
            for (int nt = 0; nt < 4; nt++) {
                int col = n0 + wc + nt * 16 + l15;
                #pragma unroll
                for (int r = 0; r < 4; r++)
                    Cb[(size_t)(row + r) * D_ + col] = (bf16)acc[mt][nt][r];
            }
        }
    } else {
        float* Cb = (float*)Cout + (size_t)b * D_ * D_;
        #pragma unroll
        for (int mt = 0; mt < 4; mt++) {
            int row = m0 + wr + mt * 16 + quad * 4;
            #pragma unroll
            for (int nt = 0; nt < 4; nt++) {
                int col = n0 + wc + nt * 16 + l15;
                float bv = bias[col];
                #pragma unroll
                for (int r = 0; r < 4; r++) {
                    float v = acc[mt][nt][r] + bv;
                    Cb[(size_t)(row + r) * D_ + col] = 0.5f * v * (1.0f + erff(v * 0.70710678118654752f));
                }
            }
        }
    }
}

// ---------------------------------------------------------------------------
extern "C" void kernel_launch(void* const* d_in, const int* in_sizes, int n_in,
                              void* d_out, int out_size, void* d_ws, size_t ws_size,
                              hipStream_t stream) {
    const float* x        = (const float*)d_in[0];
    const float* norm_adj = (const float*)d_in[1];
    const float* W_gcn_w  = (const float*)d_in[2];
    const float* W_gcn_b  = (const float*)d_in[3];
    const float* pre_w    = (const float*)d_in[4];
    const float* pre_b    = (const float*)d_in[5];
    const float* post_w   = (const float*)d_in[6];
    const float* post_b   = (const float*)d_in[7];
    const float* q_w      = (const float*)d_in[8];
    float* out = (float*)d_out;

    bf16* xbf = (bf16*)d_out;            // first 32 MiB of d_out: dead until fused2 writes
    bf16* Yt  = (bf16*)d_ws;             // 32 MiB

    const int n8_x = B_ * D_ * D_ / 8;
    const int n8_m = D_ * D_ / 8;

    const size_t MB32 = (size_t)32 * 1024 * 1024;
    if (ws_size >= MB32 + 2 * 1024 * 1024) {
        bf16* Wbf   = (bf16*)((char*)d_ws + MB32);
        bf16* adjbf = Wbf + D_ * D_;

        // 1) converts (x, W, adj) in one launch
        convert_all_k<<<2048, 256, 0, stream>>>(x, W_gcn_w, norm_adj,
                                                xbf, Wbf, adjbf, n8_x, n8_m);
        // 2) Yt[b][g][j] = sum_h W[g][h] * x[b][j][h]
        dim3 grid(16, B_);
        gemm1_k<<<grid, 256, 0, stream>>>(Wbf, xbf, (void*)Yt);
        // 3) gemm2(+gelu, rows>0) fused with quantum (row 0), one launch
        fused2_k<<<1024 + 64, 256, 0, stream>>>(adjbf, Yt, norm_adj, W_gcn_b,
                                                pre_w, pre_b, post_w, post_b,
                                                q_w, out);
    } else {
        dim3 grid(16, B_);
        convert_kernel<<<(n8_x + 255) / 256, 256, 0, stream>>>(x, xbf, n8_x);
        gemm_nt_legacy<0><<<grid, 256, 0, stream>>>(W_gcn_w, xbf, nullptr, (void*)Yt);
        gemm_nt_legacy<1><<<grid, 256, 0, stream>>>(norm_adj, Yt, W_gcn_b, (void*)out);
        quantum_k<<<B_, 64, 0, stream>>>(out, pre_w, pre_b, post_w, post_b, q_w);
    }
}

// Round 11
// 193.056 us; speedup vs baseline: 3.6266x; 1.0031x over previous
//
#include <hip/hip_runtime.h>
#include <hip/hip_bf16.h>
#include <math.h>

#define B_  64
#define D_  512
#define NQ  8
#define NL  4

typedef __bf16 bf16;
typedef float  f32x4  __attribute__((ext_vector_type(4)));
typedef bf16   bf16x8 __attribute__((ext_vector_type(8)));

__device__ __forceinline__ void async_load16(const bf16* g, bf16* l) {
    __builtin_amdgcn_global_load_lds(
        (const __attribute__((address_space(1))) void*)g,
        (__attribute__((address_space(3))) void*)l, 16, 0, 0);
}

__device__ __forceinline__ void conv8(const float* __restrict__ s, bf16* __restrict__ d) {
    const float4 v0 = *(const float4*)s;
    const float4 v1 = *(const float4*)(s + 4);
    bf16x8 p;
    p[0] = (bf16)v0.x; p[1] = (bf16)v0.y; p[2] = (bf16)v0.z; p[3] = (bf16)v0.w;
    p[4] = (bf16)v1.x; p[5] = (bf16)v1.y; p[6] = (bf16)v1.z; p[7] = (bf16)v1.w;
    *(bf16x8*)d = p;
}

// ---------------------------------------------------------------------------
// fp32 -> bf16 converts: x, W, adj in one grid-stride launch.
// ---------------------------------------------------------------------------
__global__ __launch_bounds__(256) void convert_all_k(const float* __restrict__ x,
                                                     const float* __restrict__ w,
                                                     const float* __restrict__ adj,
                                                     bf16* __restrict__ xbf,
                                                     bf16* __restrict__ wbf,
                                                     bf16* __restrict__ adjbf,
                                                     int n8x, int n8m) {
    const int total = n8x + 2 * n8m;
    for (int i = blockIdx.x * 256 + threadIdx.x; i < total; i += gridDim.x * 256) {
        if (i < n8x)            conv8(x   + (size_t)i * 8,               xbf   + (size_t)i * 8);
        else if (i < n8x + n8m) conv8(w   + (size_t)(i - n8x) * 8,       wbf   + (size_t)(i - n8x) * 8);
        else                    conv8(adj + (size_t)(i - n8x - n8m) * 8,  adjbf + (size_t)(i - n8x - n8m) * 8);
    }
}

// ---------------------------------------------------------------------------
// One 128x128 tile of the NT GEMM (proven R2 structure, 44.4 us/dispatch):
// BK=64, 2-phase double-buffer (prefetch buf^1, compute buf, 1 barrier/step),
// chunk-XOR swizzle (slot s of row r holds chunk s^(r&7); 0 conflicts
// measured), XCD-clustered virtual-tile decode (FETCH 35->20.7 MB).
// Epilogue fully unrolled (rule #20: runtime-indexed ext_vector -> scratch,
// the R4/R5 655 MB WRITE_SIZE regression).
// SKIP0 (gemm2 only): suppress row-0 stores — row 0 is wholly replaced by
// the quantum projection, computed by the fused quantum blocks.
// ---------------------------------------------------------------------------
template <int GELU, int SKIP0>
__device__ __forceinline__ void gemm128_tile(const bf16* __restrict__ A,
                                             const bf16* __restrict__ Bv,
                                             const float* __restrict__ bias,
                                             void* __restrict__ Cout,
                                             int v, int t,
                                             bf16* __restrict__ As,
                                             bf16* __restrict__ Bs) {
    const int xcd  = v & 7;
    const int idx  = v >> 3;                 // 0..127
    const int b    = (xcd << 3) | (idx >> 4);
    const int tile = idx & 15;
    const int m0   = (tile >> 2) * 128;
    const int n0   = (tile & 3) * 128;

    const int lane = t & 63;
    const int w    = t >> 6;
    const int wr   = (w >> 1) * 64;
    const int wc   = (w & 1) * 64;
    const int l15  = lane & 15;
    const int quad = lane >> 4;

    f32x4 acc[4][4];
    #pragma unroll
    for (int i = 0; i < 4; i++)
        #pragma unroll
        for (int j = 0; j < 4; j++) acc[i][j] = (f32x4)(0.0f);

    const bf16* Bb = Bv + (size_t)b * D_ * D_;

    const int rl = lane >> 3;
    const int ck = (lane & 7) ^ rl;

    // prologue: stage K-tile 0 into buffer 0
    #pragma unroll
    for (int j = 0; j < 4; j++) {
        const int rbase = w * 32 + j * 8;
        async_load16(A  + (size_t)(m0 + rbase + rl) * D_ + ck * 8, As + rbase * 64);
        async_load16(Bb + (size_t)(n0 + rbase + rl) * D_ + ck * 8, Bs + rbase * 64);
    }
    __syncthreads();

    #pragma unroll 1
    for (int s = 0; s < 8; s++) {
        const int p = s & 1;
        const bf16* Asp = As + p * (128 * 64);
        const bf16* Bsp = Bs + p * (128 * 64);
        if (s < 7) {   // prefetch next K-tile into the other buffer
            const int k0 = (s + 1) * 64;
            bf16* Asn = As + (p ^ 1) * (128 * 64);
            bf16* Bsn = Bs + (p ^ 1) * (128 * 64);
            #pragma unroll
            for (int j = 0; j < 4; j++) {
                const int rbase = w * 32 + j * 8;
                async_load16(A  + (size_t)(m0 + rbase + rl) * D_ + k0 + ck * 8, Asn + rbase * 64);
                async_load16(Bb + (size_t)(n0 + rbase + rl) * D_ + k0 + ck * 8, Bsn + rbase * 64);
            }
        }
        #pragma unroll
        for (int kk = 0; kk < 2; kk++) {
            bf16x8 af[4], bfr[4];
            #pragma unroll
            for (int mt = 0; mt < 4; mt++) {
                const int row = wr + mt * 16 + l15;
                const int sl  = (kk * 4 + quad) ^ (l15 & 7);
                af[mt] = *(const bf16x8*)&Asp[row * 64 + sl * 8];
            }
            #pragma unroll
            for (int nt = 0; nt < 4; nt++) {
                const int row = wc + nt * 16 + l15;
                const int sl  = (kk * 4 + quad) ^ (l15 & 7);
                bfr[nt] = *(const bf16x8*)&Bsp[row * 64 + sl * 8];
            }
            #pragma unroll
            for (int mt = 0; mt < 4; mt++)
                #pragma unroll
                for (int nt = 0; nt < 4; nt++)
                    acc[mt][nt] = __builtin_amdgcn_mfma_f32_16x16x32_bf16(af[mt], bfr[nt], acc[mt][nt], 0, 0, 0);
        }
        __syncthreads();
    }

    if (GELU == 0) {
        bf16* Cb = (bf16*)Cout + (size_t)b * D_ * D_;
        #pragma unroll
        for (int mt = 0; mt < 4; mt++) {
            int row = m0 + wr + mt * 16 + quad * 4;
            #pragma unroll
            for (int nt = 0; nt < 4; nt++) {
                int col = n0 + wc + nt * 16 + l15;
                #pragma unroll
                for (int r = 0; r < 4; r++)
                    Cb[(size_t)(row + r) * D_ + col] = (bf16)acc[mt][nt][r];
            }
        }
    } else {
        float* Cb = (float*)Cout + (size_t)b * D_ * D_;
        #pragma unroll
        for (int mt = 0; mt < 4; mt++) {
            int row = m0 + wr + mt * 16 + quad * 4;
            #pragma unroll
            for (int nt = 0; nt < 4; nt++) {
                int col = n0 + wc + nt * 16 + l15;
                float bv = bias[col];
                #pragma unroll
                for (int r = 0; r < 4; r++) {
                    if (SKIP0 && (row + r) == 0) continue;   // row 0 owned by quantum
                    float v2 = acc[mt][nt][r] + bv;
                    Cb[(size_t)(row + r) * D_ + col] = 0.5f * v2 * (1.0f + erff(v2 * 0.70710678118654752f));
                }
            }
        }
    }
}

// ---------------------------------------------------------------------------
// Quantum circuit core: one wave, lane l; tgt indexed [l + 64*j],
// writes the post-projection into row0[0..511].
// ---------------------------------------------------------------------------
__device__ void quantum_core(const float* __restrict__ tgt,
                             float* __restrict__ row0,
                             const float* __restrict__ pre_w,
                             const float* __restrict__ pre_b,
                             const float* __restrict__ post_w,
                             const float* __restrict__ post_b,
                             const float* __restrict__ qw,
                             int l) {
    float tg[8];
    #pragma unroll
    for (int j = 0; j < 8; j++) tg[j] = tgt[l + 64 * j];

    float ang[NQ];
    #pragma unroll
    for (int q = 0; q < NQ; q++) {
        float s = 0.f;
        #pragma unroll
        for (int j = 0; j < 8; j++) s += tg[j] * pre_w[q * D_ + l + 64 * j];
        #pragma unroll
        for (int m = 32; m >= 1; m >>= 1) s += __shfl_xor(s, m, 64);
        ang[q] = tanhf(s + pre_b[q]) * 3.14159265358979323846f;
    }

    float cw[NQ], sw[NQ];
    #pragma unroll
    for (int w = 0; w < NQ; w++) { cw[w] = cosf(0.5f * ang[w]); sw[w] = sinf(0.5f * ang[w]); }
    float re[4], im[4];
    #pragma unroll
    for (int r = 0; r < 4; r++) {
        int idx = l * 4 + r;
        float a = 1.f;
        #pragma unroll
        for (int w = 0; w < NQ; w++) a *= ((idx >> (7 - w)) & 1) ? sw[w] : cw[w];
        re[r] = a; im[r] = 0.f;
    }

    for (int lay = 0; lay < NL; lay++) {
        #pragma unroll
        for (int w = 0; w < 6; w++) {
            float th = 0.5f * qw[lay * NQ + w];
            float c = cosf(th), s = sinf(th);
            int m = 1 << (5 - w);
            #pragma unroll
            for (int r = 0; r < 4; r++) {
                float pre_ = __shfl_xor(re[r], m, 64);
                float pim_ = __shfl_xor(im[r], m, 64);
                re[r] = c * re[r] + s * pim_;
                im[r] = c * im[r] - s * pre_;
            }
        }
        {   // qubit 6 (bit 1): partner r^2
            float th = 0.5f * qw[lay * NQ + 6];
            float c = cosf(th), s = sinf(th);
            float or0 = re[0], or1 = re[1], or2 = re[2], or3 = re[3];
            float oi0 = im[0], oi1 = im[1], oi2 = im[2], oi3 = im[3];
            re[0] = c * or0 + s * oi2;  im[0] = c * oi0 - s * or2;
            re[1] = c * or1 + s * oi3;  im[1] = c * oi1 - s * or3;
            re[2] = c * or2 + s * oi0;  im[2] = c * oi2 - s * or0;
            re[3] = c * or3 + s * oi1;  im[3] = c * oi3 - s * or1;
        }
        {   // qubit 7 (bit 0): partner r^1
            float th = 0.5f * qw[lay * NQ + 7];
            float c = cosf(th), s = sinf(th);
            float or0 = re[0], or1 = re[1], or2 = re[2], or3 = re[3];
            float oi0 = im[0], oi1 = im[1], oi2 = im[2], oi3 = im[3];
            re[0] = c * or0 + s * oi1;  im[0] = c * oi0 - s * or1;
            re[1] = c * or1 + s * oi0;  im[1] = c * oi1 - s * or0;
            re[2] = c * or2 + s * oi3;  im[2] = c * oi2 - s * or3;
            re[3] = c * or3 + s * oi2;  im[3] = c * oi3 - s * or2;
        }
        #pragma unroll
        for (int w = 0; w < 5; w++) {
            int cb = 7 - w, tb = 6 - w;
            int tm = 1 << (tb - 2);
            bool ctl = (l >> (cb - 2)) & 1;
            #pragma unroll
            for (int r = 0; r < 4; r++) {
                float pre_ = __shfl_xor(re[r], tm, 64);
                float pim_ = __shfl_xor(im[r], tm, 64);
                re[r] = ctl ? pre_ : re[r];
                im[r] = ctl ? pim_ : im[r];
            }
        }
        {   // (5,6)
            bool ctl = l & 1;
            float t0 = re[0], t1 = re[1], t2 = re[2], t3 = re[3];
            float u0 = im[0], u1 = im[1], u2 = im[2], u3 = im[3];
            re[0] = ctl ? t2 : t0;  re[1] = ctl ? t3 : t1;
            re[2] = ctl ? t0 : t2;  re[3] = ctl ? t1 : t3;
            im[0] = ctl ? u2 : u0;  im[1] = ctl ? u3 : u1;
            im[2] = ctl ? u0 : u2;  im[3] = ctl ? u1 : u3;
        }
        {   // (6,7)
            float t2 = re[2], t3 = re[3], u2 = im[2], u3 = im[3];
            re[2] = t3; re[3] = t2; im[2] = u3; im[3] = u2;
        }
        {   // (7,0)
            #pragma unroll
            for (int r = 0; r < 4; r++) {
                float pre_ = __shfl_xor(re[r], 32, 64);
                float pim_ = __shfl_xor(im[r], 32, 64);
                if (r & 1) { re[r] = pre_; im[r] = pim_; }
            }
        }
    }

    float pr[4];
    #pragma unroll
    for (int r = 0; r < 4; r++) pr[r] = re[r] * re[r] + im[r] * im[r];
    float z[NQ];
    #pragma unroll
    for (int q = 0; q < NQ; q++) {
        int bit = 7 - q;
        float s = 0.f;
        #pragma unroll
        for (int r = 0; r < 4; r++) {
            int idx = l * 4 + r;
            s += ((idx >> bit) & 1) ? -pr[r] : pr[r];
        }
        #pragma unroll
        for (int m = 32; m >= 1; m >>= 1) s += __shfl_xor(s, m, 64);
        z[q] = s;
    }

    #pragma unroll
    for (int j = 0; j < 8; j++) {
        int h = l + 64 * j;
        float v = post_b[h];
        #pragma unroll
        for (int q = 0; q < NQ; q++) v += z[q] * post_w[h * NQ + q];
        row0[h] = v;
    }
}

// ---------------------------------------------------------------------------
// gemm1: standalone proven 128^2 kernel.
// ---------------------------------------------------------------------------
__global__ __launch_bounds__(256) void gemm1_k(const bf16* __restrict__ A,
                                               const bf16* __restrict__ Bv,
                                               void* __restrict__ Cout) {
    __shared__ bf16 As[2 * 128 * 64];
    __shared__ bf16 Bs[2 * 128 * 64];
    const int v = blockIdx.y * 16 + blockIdx.x;
    gemm128_tile<0, 0>(A, Bv, nullptr, Cout, v, threadIdx.x, As, Bs);
}

// ---------------------------------------------------------------------------
// fused2: gemm2(+gelu, skip row 0) for blocks 64..1087, quantum for blocks
// 0..63 (placed FIRST so the long serial circuit overlaps the gemm bulk).
// R10: quantum block v handles batch b = ((v&7)<<3)|(v>>3) — bijective
// permutation placing the block on XCD v&7 == b>>3, the XCD whose L2 holds
// batch b's Yt slice (written there by gemm1's XCD-clustered decode).
// Turns the 512 KB/batch Yt re-read into L2 hits instead of HBM/L3.
// ---------------------------------------------------------------------------
__global__ __launch_bounds__(256) void fused2_k(const bf16* __restrict__ adjb,
                                                const bf16* __restrict__ Yt,
                                                const float* __restrict__ adj_f32,
                                                const float* __restrict__ bias,
                                                const float* __restrict__ pre_w,
                                                const float* __restrict__ pre_b,
                                                const float* __restrict__ post_w,
                                                const float* __restrict__ post_b,
                                                const float* __restrict__ qw,
                                                float* __restrict__ out) {
    __shared__ bf16 As[2 * 128 * 64];
    __shared__ bf16 Bs[2 * 128 * 64];
    const int t = threadIdx.x;
    const int v = blockIdx.x;

    if (v >= 64) {
        gemm128_tile<1, 1>(adjb, Yt, bias, (void*)out, v - 64, t, As, Bs);
        return;
    }

    // ---- quantum block: XCD-aligned batch mapping (see header comment) ----
    const int b = ((v & 7) << 3) | (v >> 3);
    float* tgt_s  = (float*)As;          // 2 KB alias into gemm LDS
    float* adj0_s = (float*)Bs;          // 2 KB

    for (int i = t; i < D_; i += 256) adj0_s[i] = adj_f32[i];   // adj row 0
    __syncthreads();

    const bf16* Ytb = Yt + (size_t)b * D_ * D_;
    for (int g = t; g < D_; g += 256) {
        const bf16* yrow = Ytb + (size_t)g * D_;
        float s = bias[g];
        #pragma unroll 4
        for (int j = 0; j < D_; j += 8) {
            bf16x8 yv = *(const bf16x8*)(yrow + j);
            #pragma unroll
            for (int u = 0; u < 8; u++) s += adj0_s[j + u] * (float)yv[u];
        }
        tgt_s[g] = 0.5f * s * (1.0f + erff(s * 0.70710678118654752f));
    }
    __syncthreads();

    if (t < 64)
        quantum_core(tgt_s, out + (size_t)b * D_ * D_,
                     pre_w, pre_b, post_w, post_b, qw, t);
}

// ---------------------------------------------------------------------------
// Legacy fallback kernels (ws too small for bf16 copies)
// ---------------------------------------------------------------------------
__global__ __launch_bounds__(256) void convert_kernel(const float* __restrict__ src,
                                                      bf16* __restrict__ dst, int n8) {
    int i = blockIdx.x * 256 + threadIdx.x;
    if (i < n8) conv8(src + (size_t)i * 8, dst + (size_t)i * 8);
}

__global__ __launch_bounds__(64) void quantum_k(float* __restrict__ out,
                                                const float* __restrict__ pre_w,
                                                const float* __restrict__ pre_b,
                                                const float* __restrict__ post_w,
                                                const float* __restrict__ post_b,
                                                const float* __restrict__ qw) {
    float* row0 = out + (size_t)blockIdx.x * D_ * D_;
    quantum_core(row0, row0, pre_w, pre_b, post_w, post_b, qw, threadIdx.x);
}

#define PITCH 40
template <int GELU>
__global__ __launch_bounds__(256) void gemm_nt_legacy(const float* __restrict__ A,
                                                      const bf16* __restrict__ Bv,
                                                      const float* __restrict__ bias,
                                                      void* __restrict__ Cout) {
    __shared__ bf16 As[128 * PITCH];
    __shared__ bf16 Bs[128 * 32];
    const int b    = blockIdx.y;
    const int tile = blockIdx.x;
    const int m0   = (tile >> 2) * 128;
    const int n0   = (tile & 3) * 128;
    const int t    = threadIdx.x;
    const int lane = t & 63;
    const int w    = t >> 6;
    const int wr   = (w >> 1) * 64;
    const int wc   = (w & 1) * 64;
    const int l15  = lane & 15;
    const int quad = lane >> 4;

    f32x4 acc[4][4];
    #pragma unroll
    for (int i = 0; i < 4; i++)
        #pragma unroll
        for (int j = 0; j < 4; j++) acc[i][j] = (f32x4)(0.0f);

    const bf16* Bb = Bv + (size_t)b * D_ * D_;

    for (int k0 = 0; k0 < D_; k0 += 32) {
        for (int c = t; c < 512; c += 256) {
            int row = c >> 2, ch = c & 3;
            const float* s = A + (size_t)(m0 + row) * D_ + k0 + ch * 8;
            const float4 v0 = *(const float4*)s;
            const float4 v1 = *(const float4*)(s + 4);
            bf16x8 p;
            p[0] = (bf16)v0.x; p[1] = (bf16)v0.y; p[2] = (bf16)v0.z; p[3] = (bf16)v0.w;
            p[4] = (bf16)v1.x; p[5] = (bf16)v1.y; p[6] = (bf16)v1.z; p[7] = (bf16)v1.w;
            *(bf16x8*)&As[row * PITCH + ch * 8] = p;
        }
        {
            int rl = lane >> 2;
            int kchunk = (lane & 3) ^ ((lane >> 3) & 3);
            #pragma unroll
            for (int j = 0; j < 2; j++) {
                int rbase = w * 32 + j * 16;
                async_load16(Bb + (size_t)(n0 + rbase + rl) * D_ + k0 + kchunk * 8, &Bs[rbase * 32]);
            }
        }
        __syncthreads();
        bf16x8 af[4], bfr[4];
        #pragma unroll
        for (int mt = 0; mt < 4; mt++)
            af[mt] = *(const bf16x8*)&As[(wr + mt * 16 + l15) * PITCH + quad * 8];
        #pragma unroll
        for (int nt = 0; nt < 4; nt++) {
            int row = wc + nt * 16 + l15;
            int kx  = quad ^ ((l15 >> 1) & 3);
            bfr[nt] = *(const bf16x8*)&Bs[row * 32 + kx * 8];
        }
        #pragma unroll
        for (int mt = 0; mt < 4; mt++)
            #pragma unroll
            for (int nt = 0; nt < 4; nt++)
                acc[mt][nt] = __builtin_amdgcn_mfma_f32_16x16x32_bf16(af[mt], bfr[nt], acc[mt][nt], 0, 0, 0);
        __syncthreads();
    }

    if (GELU == 0) {
        bf16* Cb = (bf16*)Cout + (size_t)b * D_ * D_;
        #pragma unroll
        for (int mt = 0; mt < 4; mt++) {
            int row = m0 + wr + mt * 16 + quad * 4;
            #pragma unroll
            for (int nt = 0; nt < 4; nt++) {
                int col = n0 + wc + nt * 16 + l15;
                #pragma unroll
                for (int r = 0; r < 4; r++)
                    Cb[(size_t)(row + r) * D_ + col] = (bf16)acc[mt][nt][r];
            }
        }
    } else {
        float* Cb = (float*)Cout + (size_t)b * D_ * D_;
        #pragma unroll
        for (int mt = 0; mt < 4; mt++) {
            int row = m0 + wr + mt * 16 + quad * 4;
            #pragma unroll
            for (int nt = 0; nt < 4; nt++) {
                int col = n0 + wc + nt * 16 + l15;
                float bv = bias[col];
                #pragma unroll
                for (int r = 0; r < 4; r++) {
                    float v = acc[mt][nt][r] + bv;
                    Cb[(size_t)(row + r) * D_ + col] = 0.5f * v * (1.0f + erff(v * 0.70710678118654752f));
                }
            }
        }
    }
}

// ---------------------------------------------------------------------------
extern "C" void kernel_launch(void* const* d_in, const int* in_sizes, int n_in,
                              void* d_out, int out_size, void* d_ws, size_t ws_size,
                              hipStream_t stream) {
    const float* x        = (const float*)d_in[0];
    const float* norm_adj = (const float*)d_in[1];
    const float* W_gcn_w  = (const float*)d_in[2];
    const float* W_gcn_b  = (const float*)d_in[3];
    const float* pre_w    = (const float*)d_in[4];
    const float* pre_b    = (const float*)d_in[5];
    const float* post_w   = (const float*)d_in[6];
    const float* post_b   = (const float*)d_in[7];
    const float* q_w      = (const float*)d_in[8];
    float* out = (float*)d_out;

    bf16* xbf = (bf16*)d_out;            // first 32 MiB of d_out: dead until fused2 writes
    bf16* Yt  = (bf16*)d_ws;             // 32 MiB

    const int n8_x = B_ * D_ * D_ / 8;
    const int n8_m = D_ * D_ / 8;

    const size_t MB32 = (size_t)32 * 1024 * 1024;
    if (ws_size >= MB32 + 2 * 1024 * 1024) {
        bf16* Wbf   = (bf16*)((char*)d_ws + MB32);
        bf16* adjbf = Wbf + D_ * D_;

        // 1) converts (x, W, adj) in one launch
        convert_all_k<<<2048, 256, 0, stream>>>(x, W_gcn_w, norm_adj,
                                                xbf, Wbf, adjbf, n8_x, n8_m);
        // 2) Yt[b][g][j] = sum_h W[g][h] * x[b][j][h]
        dim3 grid(16, B_);
        gemm1_k<<<grid, 256, 0, stream>>>(Wbf, xbf, (void*)Yt);
        // 3) gemm2(+gelu, rows>0) fused with quantum (row 0), one launch
        fused2_k<<<1024 + 64, 256, 0, stream>>>(adjbf, Yt, norm_adj, W_gcn_b,
                                                pre_w, pre_b, post_w, post_b,
                                                q_w, out);
    } else {
        dim3 grid(16, B_);
        convert_kernel<<<(n8_x + 255) / 256, 256, 0, stream>>>(x, xbf, n8_x);
        gemm_nt_legacy<0><<<grid, 256, 0, stream>>>(W_gcn_w, xbf, nullptr, (void*)Yt);
        gemm_nt_legacy<1><<<grid, 256, 0, stream>>>(norm_adj, Yt, W_gcn_b, (void*)out);
        quantum_k<<<B_, 64, 0, stream>>>(out, pre_w, pre_b, post_w, post_b, q_w);
    }
}